// Round 7
// baseline (670.183 us; speedup 1.0000x reference)
//
#include <hip/hip_runtime.h>

#define HIDDEN 128
#define TSTEPS 512
#define NFUT 50
#define BR 16          // batch rows per block
#define THREADS 512    // 8 waves
#define HPITCH 136     // h row pitch in bf16 (272B rows: 16B-aligned for b128)

typedef __bf16 bf16x8 __attribute__((ext_vector_type(8)));
typedef float floatx4 __attribute__((ext_vector_type(4)));

union B8 { int4 i; bf16x8 v; };

#if defined(__has_builtin)
#  if __has_builtin(__builtin_amdgcn_exp2f)
#    define EXP2F(x) __builtin_amdgcn_exp2f(x)
#  else
#    define EXP2F(x) exp2f(x)
#  endif
#  if __has_builtin(__builtin_amdgcn_rcpf)
#    define RCPF(x) __builtin_amdgcn_rcpf(x)
#  else
#    define RCPF(x) (1.0f / (x))
#  endif
#else
#  define EXP2F(x) exp2f(x)
#  define RCPF(x) (1.0f / (x))
#endif

#define L2E  1.4426950408889634f
#define L2E2 2.8853900817779268f

// Two independent 8-row groups per block. Real rows live at MFMA C-rows
// 4q+{0,1} (slots {0,1,4,5,8,9,12,13}); slots 4q+{2,3} are zero/garbage and
// their gate outputs are discarded. This keeps every lane busy in ew while
// giving each group its own MFMA chain -> G1's chain runs under ew(G0).
__global__ __launch_bounds__(THREADS, 2)
void lstm_forecast_kernel(const float* __restrict__ x,
                          const float* __restrict__ W_ih,
                          const float* __restrict__ W_hh,
                          const float* __restrict__ b_ih,
                          const float* __restrict__ b_hh,
                          const float* __restrict__ fc_w,
                          const float* __restrict__ fc_b,
                          float* __restrict__ out) {
    // LDS: xa 64KB + hb 17KB + fcw 1KB ~= 82KB -> 1 block/CU
    __shared__ __align__(16) uint2  xa[TSTEPS * BR];            // (x0h,x1h),(x0r,x1r) bf16 splits
    __shared__ __align__(16) __bf16 hb[2][2][16 * HPITCH];      // [dbuf][group][slot]
    __shared__ __align__(16) float  fcw_lds[2][HIDDEN];

    const int tid  = threadIdx.x;
    const int wave = tid >> 6;
    const int lane = tid & 63;
    const int quad = lane >> 4;
    const int l15  = lane & 15;
    const int rb   = blockIdx.x * BR;

    if (tid < 256) fcw_lds[tid >> 7][tid & 127] = fc_w[tid];

    // ---- stage x as bf16 hi/lo splits: xa[t][row] ----
    {
        const int row = tid & 15;
        for (int tb = tid >> 4; tb < TSTEPS; tb += THREADS >> 4) {
            float2 xv = *(const float2*)&x[(size_t)(rb + row) * (2 * TSTEPS) + tb * 2];
            __bf16 x0h = (__bf16)xv.x, x1h = (__bf16)xv.y;
            __bf16 x0r = (__bf16)(xv.x - (float)x0h);
            __bf16 x1r = (__bf16)(xv.y - (float)x1h);
            uint2 d;
            d.x = (unsigned)__builtin_bit_cast(unsigned short, x0h) |
                  ((unsigned)__builtin_bit_cast(unsigned short, x1h) << 16);
            d.y = (unsigned)__builtin_bit_cast(unsigned short, x0r) |
                  ((unsigned)__builtin_bit_cast(unsigned short, x1r) << 16);
            xa[tb * BR + row] = d;
        }
    }
    // zero both h dbufs (fake slots stay 0 forever -> clean A-frag garbage rows)
    for (int i = tid; i < 2 * 2 * 16 * HPITCH; i += THREADS)
        ((__bf16*)hb)[i] = (__bf16)0.0f;

    // ---- weights -> registers, pre-scaled so MFMA outputs are exp2-ready ----
    // gate scale: i,f,o -> -log2(e); g -> -2*log2(e)
    bf16x8 bfrag[4][4];
    B8 bfx[4];
    float wih0[4], wih1[4], bsum[4], gs[4];
    const int u = wave * 16 + l15;
    const float fcb0 = fc_b[0], fcb1 = fc_b[1];
#pragma unroll
    for (int g = 0; g < 4; ++g) {
        gs[g] = (g == 2) ? -L2E2 : -L2E;
        const int cg = g * HIDDEN + u;
        wih0[g] = W_ih[cg * 2 + 0];
        wih1[g] = W_ih[cg * 2 + 1];
        bsum[g] = b_ih[cg] + b_hh[cg];
#pragma unroll
        for (int ks = 0; ks < 4; ++ks) {
            const float* wp = W_hh + (size_t)cg * HIDDEN + ks * 32 + quad * 8;
            bf16x8 bb;
#pragma unroll
            for (int j = 0; j < 8; ++j) bb[j] = (__bf16)(gs[g] * wp[j]);
            bfrag[g][ks] = bb;
        }
        B8 t; t.i = make_int4(0, 0, 0, 0);
        if (quad == 0) {
            const float w0s = gs[g] * wih0[g], w1s = gs[g] * wih1[g], bss = gs[g] * bsum[g];
            __bf16 w0h = (__bf16)w0s, w1h = (__bf16)w1s;
            __bf16 w0l = (__bf16)(w0s - (float)w0h);
            __bf16 w1l = (__bf16)(w1s - (float)w1h);
            __bf16 bh  = (__bf16)bss;
            __bf16 bl  = (__bf16)(bss - (float)bh);
            bf16x8 bv = {w0h, w1h, bh, bl, w0h, w1h, w0l, w1l};
            t.v = bv;
        }
        bfx[g] = t;
    }

    const unsigned ones2 = 0x3F803F80u;  // bf16(1.0) x2

    // per-lane cell state: group g, rows g*8 + 2*quad + {0,1}
    float cst0[2] = {0.f, 0.f};
    float cst1[2] = {0.f, 0.f};

    // x A-frag slot mapping: slot l15 real iff (l15&2)==0; in-group row:
    const int xr = ((l15 >> 2) << 1) + (l15 & 1);
    const unsigned rm = ((l15 & 2) == 0) ? 0xFFFFFFFFu : 0u;

    // elementwise for one group (2 states at C-rows 4q+{0,1}), pairwise rcp
    auto ewg = [&](floatx4 A0, floatx4 A1, floatx4 A2, floatx4 A3,
                   float* cs, __bf16* hd) {
        const float ea0 = EXP2F(A0[0]), ea1 = EXP2F(A0[1]);   // e^-i
        const float eb0 = EXP2F(A2[0]), eb1 = EXP2F(A2[1]);   // e^-2g
        const float ec0 = EXP2F(A1[0]), ec1 = EXP2F(A1[1]);   // e^-f
        const float a0v = 1.f + ea0, b0v = 1.f + eb0, c0v = 1.f + ec0;
        const float a1v = 1.f + ea1, b1v = 1.f + eb1, c1v = 1.f + ec1;
        const float AB0 = a0v * b0v, AB1 = a1v * b1v;
        const float D0 = AB0 * c0v, D1 = AB1 * c1v;
        const float I  = RCPF(D0 * D1);
        const float R0 = I * D1, R1 = I * D0;
        const float sf0 = AB0 * R0, sf1 = AB1 * R1;           // sigmoid(f)
        const float ig0 = (1.f - eb0) * (c0v * R0);           // sigmoid(i)*tanh(g)
        const float ig1 = (1.f - eb1) * (c1v * R1);
        const float cn0 = fmaf(sf0, cs[0], ig0);
        const float cn1 = fmaf(sf1, cs[1], ig1);
        cs[0] = cn0; cs[1] = cn1;
        const float ed0 = EXP2F(fminf(-L2E2 * cn0, 29.f));
        const float ed1 = EXP2F(fminf(-L2E2 * cn1, 29.f));
        const float eo0 = EXP2F(A3[0]), eo1 = EXP2F(A3[1]);   // e^-o
        const float E0 = (1.f + ed0) * (1.f + eo0);
        const float E1 = (1.f + ed1) * (1.f + eo1);
        const float J  = RCPF(E0 * E1);
        const float hn0 = (1.f - ed0) * (J * E1);             // sigmoid(o)*tanh(c)
        const float hn1 = (1.f - ed1) * (J * E0);
        hd[(quad * 4 + 0) * HPITCH + u] = (__bf16)hn0;
        hd[(quad * 4 + 1) * HPITCH + u] = (__bf16)hn1;
    };

    const floatx4 z = {0.f, 0.f, 0.f, 0.f};

    auto cellE = [&](int sb, int t) {
        const int db = sb ^ 1;
        bf16x8 af0[4], af1[4];
#pragma unroll
        for (int ks = 0; ks < 4; ++ks) {
            af0[ks] = *(const bf16x8*)&hb[sb][0][l15 * HPITCH + ks * 32 + quad * 8];
            af1[ks] = *(const bf16x8*)&hb[sb][1][l15 * HPITCH + ks * 32 + quad * 8];
        }
        const uint2 xd0 = xa[t * BR + xr];
        const uint2 xd1 = xa[t * BR + 8 + xr];
        B8 xf0; xf0.i = make_int4((int)(xd0.x & rm), (int)(ones2 & rm), (int)(xd0.y & rm), (int)(xd0.x & rm));
        B8 xf1; xf1.i = make_int4((int)(xd1.x & rm), (int)(ones2 & rm), (int)(xd1.y & rm), (int)(xd1.x & rm));
        floatx4 acc0[4], acc1[4];
#pragma unroll
        for (int g = 0; g < 4; ++g)
            acc0[g] = __builtin_amdgcn_mfma_f32_16x16x32_bf16(xf0.v, bfx[g].v, z, 0, 0, 0);
#pragma unroll
        for (int ks = 0; ks < 4; ++ks)
#pragma unroll
            for (int g = 0; g < 4; ++g)
                acc0[g] = __builtin_amdgcn_mfma_f32_16x16x32_bf16(af0[ks], bfrag[g][ks], acc0[g], 0, 0, 0);
#pragma unroll
        for (int g = 0; g < 4; ++g)
            acc1[g] = __builtin_amdgcn_mfma_f32_16x16x32_bf16(xf1.v, bfx[g].v, z, 0, 0, 0);
#pragma unroll
        for (int ks = 0; ks < 4; ++ks)
#pragma unroll
            for (int g = 0; g < 4; ++g)
                acc1[g] = __builtin_amdgcn_mfma_f32_16x16x32_bf16(af1[ks], bfrag[g][ks], acc1[g], 0, 0, 0);
        // ew(G0) runs on VALU while G1's MFMA chain completes in background
        ewg(acc0[0], acc0[1], acc0[2], acc0[3], cst0, &hb[db][0][0]);
        ewg(acc1[0], acc1[1], acc1[2], acc1[3], cst1, &hb[db][1][0]);
        __syncthreads();
    };

    __syncthreads();

    // ================= encode: 512 steps =================
    for (int t = 0; t < TSTEPS; t += 2) {
        cellE(0, t);
        cellE(1, t + 1);
    }

    // ========== transition: fold fc into weights =========
    // W_eff = gs*(W_hh + W_ih*fc_w) ; b_eff = gs*(b + W_ih*fc_b)
#pragma unroll
    for (int g = 0; g < 4; ++g) {
        const float bs2 = gs[g] * (bsum[g] + wih0[g] * fcb0 + wih1[g] * fcb1);
#pragma unroll
        for (int ks = 0; ks < 4; ++ks) {
            const int k0 = ks * 32 + quad * 8;
            bf16x8 bb = bfrag[g][ks];
#pragma unroll
            for (int j = 0; j < 8; ++j) {
                const float wv = (float)bb[j] + gs[g] * (wih0[g] * fcw_lds[0][k0 + j]
                                                      + wih1[g] * fcw_lds[1][k0 + j]);
                bb[j] = (__bf16)wv;
            }
            bfrag[g][ks] = bb;
        }
        // bias-only MFMA fragment for forecast init
        B8 t; t.i = make_int4(0, 0, 0, 0);
        if (quad == 0) {
            __bf16 bh = (__bf16)bs2;
            __bf16 bl = (__bf16)(bs2 - (float)bh);
            bf16x8 bv = {(__bf16)0.f, (__bf16)0.f, bh, bl,
                         (__bf16)0.f, (__bf16)0.f, (__bf16)0.f, (__bf16)0.f};
            t.v = bv;
        }
        bfx[g] = t;
    }
    // A-frag for bias init: 1.0 at k=2,3
    B8 xfF; xfF.i = make_int4(0, (int)ones2, 0, 0);

    auto cellF = [&](int sb) {
        const int db = sb ^ 1;
        bf16x8 af0[4], af1[4];
#pragma unroll
        for (int ks = 0; ks < 4; ++ks) {
            af0[ks] = *(const bf16x8*)&hb[sb][0][l15 * HPITCH + ks * 32 + quad * 8];
            af1[ks] = *(const bf16x8*)&hb[sb][1][l15 * HPITCH + ks * 32 + quad * 8];
        }
        floatx4 acc0[4], acc1[4];
#pragma unroll
        for (int g = 0; g < 4; ++g)
            acc0[g] = __builtin_amdgcn_mfma_f32_16x16x32_bf16(xfF.v, bfx[g].v, z, 0, 0, 0);
#pragma unroll
        for (int ks = 0; ks < 4; ++ks)
#pragma unroll
            for (int g = 0; g < 4; ++g)
                acc0[g] = __builtin_amdgcn_mfma_f32_16x16x32_bf16(af0[ks], bfrag[g][ks], acc0[g], 0, 0, 0);
#pragma unroll
        for (int g = 0; g < 4; ++g)
            acc1[g] = __builtin_amdgcn_mfma_f32_16x16x32_bf16(xfF.v, bfx[g].v, z, 0, 0, 0);
#pragma unroll
        for (int ks = 0; ks < 4; ++ks)
#pragma unroll
            for (int g = 0; g < 4; ++g)
                acc1[g] = __builtin_amdgcn_mfma_f32_16x16x32_bf16(af1[ks], bfrag[g][ks], acc1[g], 0, 0, 0);
        ewg(acc0[0], acc0[1], acc0[2], acc0[3], cst0, &hb[db][0][0]);
        ewg(acc1[0], acc1[1], acc1[2], acc1[3], cst1, &hb[db][1][0]);
        __syncthreads();
    };

    // y output only (no feedback): wave0 computes while others run MFMA
    auto emitY = [&](int sb, int f) {
        if (wave == 0) {
            const int r = lane & 15, seg = lane >> 4;
            const int g = r >> 3, rr = r & 7;
            const int slot = ((rr >> 1) << 2) + (rr & 1);
            const __bf16* hp = &hb[sb][g][slot * HPITCH + seg * 32];
            float p0 = 0.f, p1 = 0.f;
#pragma unroll
            for (int js = 0; js < 4; ++js) {
                bf16x8 hv = *(const bf16x8*)&hp[js * 8];
                const float4* f0 = (const float4*)&fcw_lds[0][seg * 32 + js * 8];
                const float4* f1 = (const float4*)&fcw_lds[1][seg * 32 + js * 8];
                float4 a0 = f0[0], b0 = f0[1], a1 = f1[0], b1 = f1[1];
                p0 += (float)hv[0]*a0.x + (float)hv[1]*a0.y + (float)hv[2]*a0.z + (float)hv[3]*a0.w
                    + (float)hv[4]*b0.x + (float)hv[5]*b0.y + (float)hv[6]*b0.z + (float)hv[7]*b0.w;
                p1 += (float)hv[0]*a1.x + (float)hv[1]*a1.y + (float)hv[2]*a1.z + (float)hv[3]*a1.w
                    + (float)hv[4]*b1.x + (float)hv[5]*b1.y + (float)hv[6]*b1.z + (float)hv[7]*b1.w;
            }
            p0 += __shfl_xor(p0, 16); p0 += __shfl_xor(p0, 32);
            p1 += __shfl_xor(p1, 16); p1 += __shfl_xor(p1, 32);
            if (seg == 0) {
                float* op = &out[(size_t)(rb + r) * (2 * NFUT) + f * 2];
                op[0] = p0 + fcb0;
                op[1] = p1 + fcb1;
            }
        }
    };

    // ================= forecast: 50 steps ================
    for (int f = 0; f < NFUT; f += 2) {
        emitY(0, f);
        cellF(0);
        emitY(1, f + 1);
        cellF(1);
    }
}

extern "C" void kernel_launch(void* const* d_in, const int* in_sizes, int n_in,
                              void* d_out, int out_size, void* d_ws, size_t ws_size,
                              hipStream_t stream) {
    const float* x    = (const float*)d_in[0];
    const float* W_ih = (const float*)d_in[1];
    const float* W_hh = (const float*)d_in[2];
    const float* b_ih = (const float*)d_in[3];
    const float* b_hh = (const float*)d_in[4];
    const float* fc_w = (const float*)d_in[5];
    const float* fc_b = (const float*)d_in[6];
    float* out = (float*)d_out;

    const int B = in_sizes[0] / (TSTEPS * 2);   // 4096
    const int grid = B / BR;                    // 256 blocks, 1 per CU
    lstm_forecast_kernel<<<grid, THREADS, 0, stream>>>(x, W_ih, W_hh, b_ih, b_hh, fc_w, fc_b, out);
}

// Round 8
// 610.580 us; speedup vs baseline: 1.0976x; 1.0976x over previous
//
#include <hip/hip_runtime.h>

#define HIDDEN 128
#define TSTEPS 512
#define NFUT 50
#define BR 16          // batch rows per block
#define THREADS 256    // 4 waves, 1 per SIMD -> intra-wave MFMA/VALU overlap
#define HPITCH 136     // h row pitch in bf16 (272B rows: 16B-aligned for b128)

typedef __bf16 bf16x8 __attribute__((ext_vector_type(8)));
typedef float floatx4 __attribute__((ext_vector_type(4)));

union B8 { int4 i; bf16x8 v; };

#if defined(__has_builtin)
#  if __has_builtin(__builtin_amdgcn_exp2f)
#    define EXP2F(x) __builtin_amdgcn_exp2f(x)
#  else
#    define EXP2F(x) exp2f(x)
#  endif
#  if __has_builtin(__builtin_amdgcn_rcpf)
#    define RCPF(x) __builtin_amdgcn_rcpf(x)
#  else
#    define RCPF(x) (1.0f / (x))
#  endif
#else
#  define EXP2F(x) exp2f(x)
#  define RCPF(x) (1.0f / (x))
#endif

#define L2E  1.4426950408889634f
#define L2E2 2.8853900817779268f

__global__ __launch_bounds__(THREADS, 1)
void lstm_forecast_kernel(const float* __restrict__ x,
                          const float* __restrict__ W_ih,
                          const float* __restrict__ W_hh,
                          const float* __restrict__ b_ih,
                          const float* __restrict__ b_hh,
                          const float* __restrict__ fc_w,
                          const float* __restrict__ fc_b,
                          float* __restrict__ out) {
    // LDS: xa 64.1KB + h 8.5KB + fcw 1KB ~= 74KB -> 1 block/CU (4 waves, 1/SIMD)
    __shared__ __align__(16) uint2  xa[(TSTEPS + 1) * BR];  // +1 zero pad row
    __shared__ __align__(16) __bf16 h_lds[2][BR * HPITCH];  // double-buffered h
    __shared__ __align__(16) float  fcw_lds[2][HIDDEN];

    const int tid  = threadIdx.x;
    const int wave = tid >> 6;           // 0..3
    const int lane = tid & 63;
    const int quad = lane >> 4;
    const int l15  = lane & 15;
    const int rb   = blockIdx.x * BR;

    fcw_lds[tid >> 7][tid & 127] = fc_w[tid];   // 256 threads = exactly 256 values

    // ---- stage x as bf16 hi/lo splits: xa[t][row]; row TSTEPS zeroed ----
    {
        const int row = tid & 15;
        for (int tb = tid >> 4; tb < TSTEPS + 1; tb += THREADS >> 4) {
            float2 xv = make_float2(0.f, 0.f);
            if (tb < TSTEPS)
                xv = *(const float2*)&x[(size_t)(rb + row) * (2 * TSTEPS) + tb * 2];
            __bf16 x0h = (__bf16)xv.x, x1h = (__bf16)xv.y;
            __bf16 x0r = (__bf16)(xv.x - (float)x0h);
            __bf16 x1r = (__bf16)(xv.y - (float)x1h);
            uint2 d;
            d.x = (unsigned)__builtin_bit_cast(unsigned short, x0h) |
                  ((unsigned)__builtin_bit_cast(unsigned short, x1h) << 16);
            d.y = (unsigned)__builtin_bit_cast(unsigned short, x0r) |
                  ((unsigned)__builtin_bit_cast(unsigned short, x1r) << 16);
            xa[tb * BR + row] = d;
        }
    }
    for (int i = tid; i < BR * HPITCH; i += THREADS) h_lds[0][i] = (__bf16)0.0f;

    // ---- weights -> registers, pre-scaled so MFMA outputs are exp2-ready ----
    // wave owns units u[ch] = wave*32 + ch*16 + l15, ch in {0,1}
    // gate scale: i,f,o -> -log2(e); g -> -2*log2(e)
    bf16x8 bfrag[2][4][4];
    B8 bfx[2][4];
    float wih0[2][4], wih1[2][4], bsum[2][4], gs[4];
    int u[2];
    u[0] = wave * 32 + l15;
    u[1] = u[0] + 16;
    const float fcb0 = fc_b[0], fcb1 = fc_b[1];
#pragma unroll
    for (int ch = 0; ch < 2; ++ch) {
#pragma unroll
        for (int g = 0; g < 4; ++g) {
            gs[g] = (g == 2) ? -L2E2 : -L2E;
            const int cg = g * HIDDEN + u[ch];
            wih0[ch][g] = W_ih[cg * 2 + 0];
            wih1[ch][g] = W_ih[cg * 2 + 1];
            bsum[ch][g] = b_ih[cg] + b_hh[cg];
#pragma unroll
            for (int ks = 0; ks < 4; ++ks) {
                const float* wp = W_hh + (size_t)cg * HIDDEN + ks * 32 + quad * 8;
                bf16x8 bb;
#pragma unroll
                for (int j = 0; j < 8; ++j) bb[j] = (__bf16)(gs[g] * wp[j]);
                bfrag[ch][g][ks] = bb;
            }
            B8 t; t.i = make_int4(0, 0, 0, 0);
            if (quad == 0) {
                const float w0s = gs[g] * wih0[ch][g], w1s = gs[g] * wih1[ch][g];
                const float bss = gs[g] * bsum[ch][g];
                __bf16 w0h = (__bf16)w0s, w1h = (__bf16)w1s;
                __bf16 w0l = (__bf16)(w0s - (float)w0h);
                __bf16 w1l = (__bf16)(w1s - (float)w1h);
                __bf16 bh  = (__bf16)bss;
                __bf16 bl  = (__bf16)(bss - (float)bh);
                bf16x8 bv = {w0h, w1h, bh, bl, w0h, w1h, w0l, w1l};
                t.v = bv;
            }
            bfx[ch][g] = t;
        }
    }

    const unsigned ones2 = 0x3F803F80u;  // bf16(1.0) x2

    float cst[2][4] = {{0.f, 0.f, 0.f, 0.f}, {0.f, 0.f, 0.f, 0.f}};

    // elementwise for one ch (4 states), pairwise-batched reciprocals
    auto ew = [&](const floatx4* a, float* cs, int uc, __bf16* hd) {
        float hn[4];
#pragma unroll
        for (int p = 0; p < 2; ++p) {
            const int r0 = 2 * p, r1 = 2 * p + 1;
            const float ea0 = EXP2F(a[0][r0]), ea1 = EXP2F(a[0][r1]);   // e^-i
            const float eb0 = EXP2F(a[2][r0]), eb1 = EXP2F(a[2][r1]);   // e^-2g
            const float ec0 = EXP2F(a[1][r0]), ec1 = EXP2F(a[1][r1]);   // e^-f
            const float A0 = 1.f + ea0, B0 = 1.f + eb0, C0 = 1.f + ec0;
            const float A1v = 1.f + ea1, B1v = 1.f + eb1, C1v = 1.f + ec1;
            const float AB0 = A0 * B0, AB1 = A1v * B1v;
            const float D0 = AB0 * C0, D1 = AB1 * C1v;
            const float I  = RCPF(D0 * D1);
            const float R0 = I * D1, R1 = I * D0;
            const float sf0 = AB0 * R0, sf1 = AB1 * R1;             // sigmoid(f)
            const float ig0 = (1.f - eb0) * (C0 * R0);              // sigmoid(i)*tanh(g)
            const float ig1 = (1.f - eb1) * (C1v * R1);
            const float cn0 = fmaf(sf0, cs[r0], ig0);
            const float cn1 = fmaf(sf1, cs[r1], ig1);
            cs[r0] = cn0; cs[r1] = cn1;
            const float ed0 = EXP2F(fminf(-L2E2 * cn0, 29.f));
            const float ed1 = EXP2F(fminf(-L2E2 * cn1, 29.f));
            const float eo0 = EXP2F(a[3][r0]), eo1 = EXP2F(a[3][r1]);  // e^-o
            const float E0 = (1.f + ed0) * (1.f + eo0);
            const float E1 = (1.f + ed1) * (1.f + eo1);
            const float J  = RCPF(E0 * E1);
            hn[r0] = (1.f - ed0) * (J * E1);                        // sigmoid(o)*tanh(c)
            hn[r1] = (1.f - ed1) * (J * E0);
        }
#pragma unroll
        for (int r = 0; r < 4; ++r)
            hd[(quad * 4 + r) * HPITCH + uc] = (__bf16)hn[r];
    };

    const floatx4 z = {0.f, 0.f, 0.f, 0.f};

    // one encode step: 40 MFMAs (8 independent 5-deep chains) then 2x ew.
    // At 1 wave/SIMD the scheduler overlaps ew VALU with draining MFMA chains.
    auto cellE = [&](const __bf16* hs, __bf16* hd, int t) {
        bf16x8 af[4];
#pragma unroll
        for (int ks = 0; ks < 4; ++ks)
            af[ks] = *(const bf16x8*)&hs[l15 * HPITCH + ks * 32 + quad * 8];
        const uint2 xd = xa[t * BR + l15];
        B8 xf; xf.i = make_int4((int)xd.x, (int)ones2, (int)xd.y, (int)xd.x);
        floatx4 acc[2][4];
#pragma unroll
        for (int ch = 0; ch < 2; ++ch)
#pragma unroll
            for (int g = 0; g < 4; ++g)
                acc[ch][g] = __builtin_amdgcn_mfma_f32_16x16x32_bf16(xf.v, bfx[ch][g].v, z, 0, 0, 0);
#pragma unroll
        for (int ks = 0; ks < 4; ++ks)
#pragma unroll
            for (int ch = 0; ch < 2; ++ch)
#pragma unroll
                for (int g = 0; g < 4; ++g)
                    acc[ch][g] = __builtin_amdgcn_mfma_f32_16x16x32_bf16(af[ks], bfrag[ch][g][ks], acc[ch][g], 0, 0, 0);
        ew(acc[0], cst[0], u[0], hd);
        ew(acc[1], cst[1], u[1], hd);
        __syncthreads();
    };

    __syncthreads();

    // ================= encode: 512 steps =================
    for (int t = 0; t < TSTEPS; t += 2) {
        cellE(h_lds[0], h_lds[1], t);
        cellE(h_lds[1], h_lds[0], t + 1);
    }

    // ========== transition: fold fc into weights =========
    // W_eff = gs*(W_hh + W_ih*fc_w) ; b_eff = gs*(b + W_ih*fc_b)
#pragma unroll
    for (int ch = 0; ch < 2; ++ch) {
#pragma unroll
        for (int g = 0; g < 4; ++g) {
            const float bs2 = gs[g] * (bsum[ch][g] + wih0[ch][g] * fcb0 + wih1[ch][g] * fcb1);
#pragma unroll
            for (int ks = 0; ks < 4; ++ks) {
                const int k0 = ks * 32 + quad * 8;
                bf16x8 bb = bfrag[ch][g][ks];
#pragma unroll
                for (int j = 0; j < 8; ++j) {
                    const float wv = (float)bb[j] + gs[g] * (wih0[ch][g] * fcw_lds[0][k0 + j]
                                                          + wih1[ch][g] * fcw_lds[1][k0 + j]);
                    bb[j] = (__bf16)wv;
                }
                bfrag[ch][g][ks] = bb;
            }
            // bias-only fragment for forecast init
            B8 t; t.i = make_int4(0, 0, 0, 0);
            if (quad == 0) {
                __bf16 bh = (__bf16)bs2;
                __bf16 bl = (__bf16)(bs2 - (float)bh);
                bf16x8 bv = {(__bf16)0.f, (__bf16)0.f, bh, bl,
                             (__bf16)0.f, (__bf16)0.f, (__bf16)0.f, (__bf16)0.f};
                t.v = bv;
            }
            bfx[ch][g] = t;
        }
    }
    B8 xfF; xfF.i = make_int4(0, (int)ones2, 0, 0);   // A-frag selecting bias rows

    auto cellF = [&](const __bf16* hs, __bf16* hd) {
        bf16x8 af[4];
#pragma unroll
        for (int ks = 0; ks < 4; ++ks)
            af[ks] = *(const bf16x8*)&hs[l15 * HPITCH + ks * 32 + quad * 8];
        floatx4 acc[2][4];
#pragma unroll
        for (int ch = 0; ch < 2; ++ch)
#pragma unroll
            for (int g = 0; g < 4; ++g)
                acc[ch][g] = __builtin_amdgcn_mfma_f32_16x16x32_bf16(xfF.v, bfx[ch][g].v, z, 0, 0, 0);
#pragma unroll
        for (int ks = 0; ks < 4; ++ks)
#pragma unroll
            for (int ch = 0; ch < 2; ++ch)
#pragma unroll
                for (int g = 0; g < 4; ++g)
                    acc[ch][g] = __builtin_amdgcn_mfma_f32_16x16x32_bf16(af[ks], bfrag[ch][g][ks], acc[ch][g], 0, 0, 0);
        ew(acc[0], cst[0], u[0], hd);
        ew(acc[1], cst[1], u[1], hd);
        __syncthreads();
    };

    // y output only (no feedback): wave0 computes while others run MFMA
    auto emitY = [&](const __bf16* hs, int f) {
        if (wave == 0) {
            const int r = lane & 15, seg = lane >> 4;
            const __bf16* hp = &hs[r * HPITCH + seg * 32];
            float p0 = 0.f, p1 = 0.f;
#pragma unroll
            for (int js = 0; js < 4; ++js) {
                bf16x8 hv = *(const bf16x8*)&hp[js * 8];
                const float4* f0 = (const float4*)&fcw_lds[0][seg * 32 + js * 8];
                const float4* f1 = (const float4*)&fcw_lds[1][seg * 32 + js * 8];
                float4 a0 = f0[0], b0 = f0[1], a1 = f1[0], b1 = f1[1];
                p0 += (float)hv[0]*a0.x + (float)hv[1]*a0.y + (float)hv[2]*a0.z + (float)hv[3]*a0.w
                    + (float)hv[4]*b0.x + (float)hv[5]*b0.y + (float)hv[6]*b0.z + (float)hv[7]*b0.w;
                p1 += (float)hv[0]*a1.x + (float)hv[1]*a1.y + (float)hv[2]*a1.z + (float)hv[3]*a1.w
                    + (float)hv[4]*b1.x + (float)hv[5]*b1.y + (float)hv[6]*b1.z + (float)hv[7]*b1.w;
            }
            p0 += __shfl_xor(p0, 16); p0 += __shfl_xor(p0, 32);
            p1 += __shfl_xor(p1, 16); p1 += __shfl_xor(p1, 32);
            if (seg == 0) {
                float* op = &out[(size_t)(rb + r) * (2 * NFUT) + f * 2];
                op[0] = p0 + fcb0;
                op[1] = p1 + fcb1;
            }
        }
    };

    // ================= forecast: 50 steps ================
    for (int f = 0; f < NFUT; f += 2) {
        emitY(h_lds[0], f);
        cellF(h_lds[0], h_lds[1]);
        emitY(h_lds[1], f + 1);
        cellF(h_lds[1], h_lds[0]);
    }
}

extern "C" void kernel_launch(void* const* d_in, const int* in_sizes, int n_in,
                              void* d_out, int out_size, void* d_ws, size_t ws_size,
                              hipStream_t stream) {
    const float* x    = (const float*)d_in[0];
    const float* W_ih = (const float*)d_in[1];
    const float* W_hh = (const float*)d_in[2];
    const float* b_ih = (const float*)d_in[3];
    const float* b_hh = (const float*)d_in[4];
    const float* fc_w = (const float*)d_in[5];
    const float* fc_b = (const float*)d_in[6];
    float* out = (float*)d_out;

    const int B = in_sizes[0] / (TSTEPS * 2);   // 4096
    const int grid = B / BR;                    // 256 blocks, 1 per CU
    lstm_forecast_kernel<<<grid, THREADS, 0, stream>>>(x, W_ih, W_hh, b_ih, b_hh, fc_w, fc_b, out);
}

// Round 9
// 495.613 us; speedup vs baseline: 1.3522x; 1.2320x over previous
//
#include <hip/hip_runtime.h>

#define HIDDEN 128
#define TSTEPS 512
#define NFUT 50
#define BR 16          // batch rows per block
#define THREADS 512    // 8 waves, 2 per SIMD
#define HPITCH 136     // h row pitch in bf16 (272B rows: 16B-aligned for b128)

typedef __bf16 bf16x8 __attribute__((ext_vector_type(8)));
typedef float floatx4 __attribute__((ext_vector_type(4)));
typedef float f32x2 __attribute__((ext_vector_type(2)));

union B8 { int4 i; bf16x8 v; };

#if defined(__has_builtin)
#  if __has_builtin(__builtin_amdgcn_exp2f)
#    define EXP2F(x) __builtin_amdgcn_exp2f(x)
#  else
#    define EXP2F(x) exp2f(x)
#  endif
#  if __has_builtin(__builtin_amdgcn_rcpf)
#    define RCPF(x) __builtin_amdgcn_rcpf(x)
#  else
#    define RCPF(x) (1.0f / (x))
#  endif
#  if __has_builtin(__builtin_amdgcn_s_setprio)
#    define SETPRIO(p) __builtin_amdgcn_s_setprio(p)
#  else
#    define SETPRIO(p)
#  endif
#else
#  define EXP2F(x) exp2f(x)
#  define RCPF(x) (1.0f / (x))
#  define SETPRIO(p)
#endif

#define L2E  1.4426950408889634f
#define L2E2 2.8853900817779268f

__global__ __launch_bounds__(THREADS, 2)
void lstm_forecast_kernel(const float* __restrict__ x,
                          const float* __restrict__ W_ih,
                          const float* __restrict__ W_hh,
                          const float* __restrict__ b_ih,
                          const float* __restrict__ b_hh,
                          const float* __restrict__ fc_w,
                          const float* __restrict__ fc_b,
                          float* __restrict__ out) {
    // LDS: xa 64KB + h 8.5KB + fcw 1KB ~= 74KB -> 1 block/CU
    __shared__ __align__(16) uint2  xa[TSTEPS * BR];        // (x0h,x1h),(x0r,x1r) bf16 splits
    __shared__ __align__(16) __bf16 h_lds[2][BR * HPITCH];  // double-buffered h
    __shared__ __align__(16) float  fcw_lds[2][HIDDEN];

    const int tid  = threadIdx.x;
    const int wave = tid >> 6;
    const int lane = tid & 63;
    const int quad = lane >> 4;
    const int l15  = lane & 15;
    const int rb   = blockIdx.x * BR;

    if (tid < 256) fcw_lds[tid >> 7][tid & 127] = fc_w[tid];

    // ---- stage x as bf16 hi/lo splits: xa[t][row] ----
    {
        const int row = tid & 15;
        for (int tb = tid >> 4; tb < TSTEPS; tb += THREADS >> 4) {
            float2 xv = *(const float2*)&x[(size_t)(rb + row) * (2 * TSTEPS) + tb * 2];
            __bf16 x0h = (__bf16)xv.x, x1h = (__bf16)xv.y;
            __bf16 x0r = (__bf16)(xv.x - (float)x0h);
            __bf16 x1r = (__bf16)(xv.y - (float)x1h);
            uint2 d;
            d.x = (unsigned)__builtin_bit_cast(unsigned short, x0h) |
                  ((unsigned)__builtin_bit_cast(unsigned short, x1h) << 16);
            d.y = (unsigned)__builtin_bit_cast(unsigned short, x0r) |
                  ((unsigned)__builtin_bit_cast(unsigned short, x1r) << 16);
            xa[tb * BR + row] = d;
        }
    }
    for (int i = tid; i < BR * HPITCH; i += THREADS) h_lds[0][i] = (__bf16)0.0f;

    // ---- weights -> registers, pre-scaled so MFMA outputs are exp2-ready ----
    // gate scale: i,f,o -> -log2(e); g -> -2*log2(e)
    bf16x8 bfrag[4][4];   // scaled W_hh (later W_eff) fragments
    B8 bfx[4];            // scaled x+bias MFMA B-fragments (quad0 slots)
    float wih0[4], wih1[4], bsum[4], gs[4];
    const int u = wave * 16 + l15;
    const float fcb0 = fc_b[0], fcb1 = fc_b[1];
#pragma unroll
    for (int g = 0; g < 4; ++g) {
        gs[g] = (g == 2) ? -L2E2 : -L2E;
        const int cg = g * HIDDEN + u;
        wih0[g] = W_ih[cg * 2 + 0];
        wih1[g] = W_ih[cg * 2 + 1];
        bsum[g] = b_ih[cg] + b_hh[cg];
#pragma unroll
        for (int ks = 0; ks < 4; ++ks) {
            const float* wp = W_hh + (size_t)cg * HIDDEN + ks * 32 + quad * 8;
            bf16x8 bb;
#pragma unroll
            for (int j = 0; j < 8; ++j) bb[j] = (__bf16)(gs[g] * wp[j]);
            bfrag[g][ks] = bb;
        }
        B8 t; t.i = make_int4(0, 0, 0, 0);
        if (quad == 0) {
            const float w0s = gs[g] * wih0[g], w1s = gs[g] * wih1[g], bss = gs[g] * bsum[g];
            __bf16 w0h = (__bf16)w0s, w1h = (__bf16)w1s;
            __bf16 w0l = (__bf16)(w0s - (float)w0h);
            __bf16 w1l = (__bf16)(w1s - (float)w1h);
            __bf16 bh  = (__bf16)bss;
            __bf16 bl  = (__bf16)(bss - (float)bh);
            bf16x8 bv = {w0h, w1h, bh, bl, w0h, w1h, w0l, w1l};
            t.v = bv;
        }
        bfx[g] = t;
    }

    const unsigned ones2 = 0x3F803F80u;  // bf16(1.0) x2 (B rows are 0 off-quad0)

    f32x2 cst[2] = {{0.f, 0.f}, {0.f, 0.f}};   // 4 cell states as 2 packed pairs

    // elementwise on packed f32 pairs (v_pk_* for muls/adds; trans scalarized).
    // Same math as R4: 5 exp + 2 rcp per state.
    auto ew = [&](floatx4 a0, floatx4 a1, floatx4 a2, floatx4 a3, __bf16* hd) {
#pragma unroll
        for (int p = 0; p < 2; ++p) {
            const f32x2 ap0 = {a0[2*p], a0[2*p+1]};
            const f32x2 ap1 = {a1[2*p], a1[2*p+1]};
            const f32x2 ap2 = {a2[2*p], a2[2*p+1]};
            const f32x2 ap3 = {a3[2*p], a3[2*p+1]};
            f32x2 ea, eb, ec;
            ea.x = EXP2F(ap0.x); ea.y = EXP2F(ap0.y);   // e^-i (scaled)
            eb.x = EXP2F(ap2.x); eb.y = EXP2F(ap2.y);   // e^-2g
            ec.x = EXP2F(ap1.x); ec.y = EXP2F(ap1.y);   // e^-f
            const f32x2 A1 = 1.f + ea, B1 = 1.f + eb, C1 = 1.f + ec;
            const f32x2 P  = A1 * B1;
            const f32x2 PC = P * C1;
            f32x2 R;
            R.x = RCPF(PC.x); R.y = RCPF(PC.y);
            const f32x2 sfv = P * R;                    // sigmoid(f)
            const f32x2 igv = (1.f - eb) * (C1 * R);    // sigmoid(i)*tanh(g)
            const f32x2 cn  = sfv * cst[p] + igv;
            cst[p] = cn;
            const f32x2 am = -L2E2 * cn;
            f32x2 ed, eo;
            ed.x = EXP2F(fminf(am.x, 80.f));            // e^-2c (clamped)
            ed.y = EXP2F(fminf(am.y, 80.f));
            eo.x = EXP2F(ap3.x); eo.y = EXP2F(ap3.y);   // e^-o
            const f32x2 E = (1.f + ed) * (1.f + eo);
            f32x2 R2;
            R2.x = RCPF(E.x); R2.y = RCPF(E.y);
            const f32x2 hn = (1.f - ed) * R2;           // sigmoid(o)*tanh(c)
            hd[(quad * 4 + 2*p + 0) * HPITCH + u] = (__bf16)hn.x;
            hd[(quad * 4 + 2*p + 1) * HPITCH + u] = (__bf16)hn.y;
        }
    };

    auto cellE = [&](const __bf16* hs, __bf16* hd, int t) {
        const uint2 xd = xa[t * BR + l15];            // quad-broadcast, conflict-free
        B8 xf; xf.i = make_int4((int)xd.x, (int)ones2, (int)xd.y, (int)xd.x);
        bf16x8 af[4];
#pragma unroll
        for (int ks = 0; ks < 4; ++ks)
            af[ks] = *(const bf16x8*)&hs[l15 * HPITCH + ks * 32 + quad * 8];
        const floatx4 z = {0.f, 0.f, 0.f, 0.f};
        floatx4 acc[4];
        SETPRIO(1);                                    // prioritize MFMA issue
#pragma unroll
        for (int g = 0; g < 4; ++g)   // scaled x + bias folded into MFMA, zero-C init
            acc[g] = __builtin_amdgcn_mfma_f32_16x16x32_bf16(xf.v, bfx[g].v, z, 0, 0, 0);
#pragma unroll
        for (int ks = 0; ks < 4; ++ks)
#pragma unroll
            for (int g = 0; g < 4; ++g)
                acc[g] = __builtin_amdgcn_mfma_f32_16x16x32_bf16(af[ks], bfrag[g][ks], acc[g], 0, 0, 0);
        SETPRIO(0);                                    // yield to sibling wave's MFMA
        ew(acc[0], acc[1], acc[2], acc[3], hd);
        __syncthreads();
    };

    __syncthreads();

    // ================= encode: 512 steps =================
    for (int t = 0; t < TSTEPS; t += 2) {
        cellE(h_lds[0], h_lds[1], t);
        cellE(h_lds[1], h_lds[0], t + 1);
    }

    // ========== transition: fold fc into weights =========
    // W_eff = gs*(W_hh + W_ih*fc_w) ; b_eff = gs*(b + W_ih*fc_b)
    float bs2[4];
#pragma unroll
    for (int g = 0; g < 4; ++g) {
        bs2[g] = gs[g] * (bsum[g] + wih0[g] * fcb0 + wih1[g] * fcb1);
#pragma unroll
        for (int ks = 0; ks < 4; ++ks) {
            const int k0 = ks * 32 + quad * 8;
            bf16x8 bb = bfrag[g][ks];
#pragma unroll
            for (int j = 0; j < 8; ++j) {
                const float wv = (float)bb[j] + gs[g] * (wih0[g] * fcw_lds[0][k0 + j]
                                                      + wih1[g] * fcw_lds[1][k0 + j]);
                bb[j] = (__bf16)wv;
            }
            bfrag[g][ks] = bb;
        }
    }

    auto cellF = [&](const __bf16* hs, __bf16* hd) {
        bf16x8 af[4];
#pragma unroll
        for (int ks = 0; ks < 4; ++ks)
            af[ks] = *(const bf16x8*)&hs[l15 * HPITCH + ks * 32 + quad * 8];
        floatx4 acc[4];
#pragma unroll
        for (int g = 0; g < 4; ++g)
            acc[g] = (floatx4){bs2[g], bs2[g], bs2[g], bs2[g]};  // exact fp32 scaled bias
        SETPRIO(1);
#pragma unroll
        for (int ks = 0; ks < 4; ++ks)
#pragma unroll
            for (int g = 0; g < 4; ++g)
                acc[g] = __builtin_amdgcn_mfma_f32_16x16x32_bf16(af[ks], bfrag[g][ks], acc[g], 0, 0, 0);
        SETPRIO(0);
        ew(acc[0], acc[1], acc[2], acc[3], hd);
        __syncthreads();
    };

    // y output only (no feedback): wave0 computes while others run MFMA
    auto emitY = [&](const __bf16* hs, int f) {
        if (wave == 0) {
            const int r = lane & 15, seg = lane >> 4;
            const __bf16* hp = &hs[r * HPITCH + seg * 32];
            float p0 = 0.f, p1 = 0.f;
#pragma unroll
            for (int js = 0; js < 4; ++js) {
                bf16x8 hv = *(const bf16x8*)&hp[js * 8];
                const float4* f0 = (const float4*)&fcw_lds[0][seg * 32 + js * 8];
                const float4* f1 = (const float4*)&fcw_lds[1][seg * 32 + js * 8];
                float4 a0 = f0[0], b0 = f0[1], a1 = f1[0], b1 = f1[1];
                p0 += (float)hv[0]*a0.x + (float)hv[1]*a0.y + (float)hv[2]*a0.z + (float)hv[3]*a0.w
                    + (float)hv[4]*b0.x + (float)hv[5]*b0.y + (float)hv[6]*b0.z + (float)hv[7]*b0.w;
                p1 += (float)hv[0]*a1.x + (float)hv[1]*a1.y + (float)hv[2]*a1.z + (float)hv[3]*a1.w
                    + (float)hv[4]*b1.x + (float)hv[5]*b1.y + (float)hv[6]*b1.z + (float)hv[7]*b1.w;
            }
            p0 += __shfl_xor(p0, 16); p0 += __shfl_xor(p0, 32);
            p1 += __shfl_xor(p1, 16); p1 += __shfl_xor(p1, 32);
            if (seg == 0) {
                float* op = &out[(size_t)(rb + r) * (2 * NFUT) + f * 2];
                op[0] = p0 + fcb0;
                op[1] = p1 + fcb1;
            }
        }
    };

    // ================= forecast: 50 steps ================
    for (int f = 0; f < NFUT; f += 2) {
        emitY(h_lds[0], f);
        cellF(h_lds[0], h_lds[1]);
        emitY(h_lds[1], f + 1);
        cellF(h_lds[1], h_lds[0]);
    }
}

extern "C" void kernel_launch(void* const* d_in, const int* in_sizes, int n_in,
                              void* d_out, int out_size, void* d_ws, size_t ws_size,
                              hipStream_t stream) {
    const float* x    = (const float*)d_in[0];
    const float* W_ih = (const float*)d_in[1];
    const float* W_hh = (const float*)d_in[2];
    const float* b_ih = (const float*)d_in[3];
    const float* b_hh = (const float*)d_in[4];
    const float* fc_w = (const float*)d_in[5];
    const float* fc_b = (const float*)d_in[6];
    float* out = (float*)d_out;

    const int B = in_sizes[0] / (TSTEPS * 2);   // 4096
    const int grid = B / BR;                    // 256 blocks, 1 per CU
    lstm_forecast_kernel<<<grid, THREADS, 0, stream>>>(x, W_ih, W_hh, b_ih, b_hh, fc_w, fc_b, out);
}

// Round 10
// 493.662 us; speedup vs baseline: 1.3576x; 1.0040x over previous
//
#include <hip/hip_runtime.h>

#define HIDDEN 128
#define TSTEPS 512
#define NFUT 50
#define BR 16          // batch rows per block
#define THREADS 512    // 8 waves, 2 per SIMD
#define HPITCH 136     // h row pitch in bf16 (272B rows: 16B-aligned for b128)

typedef __bf16 bf16x8 __attribute__((ext_vector_type(8)));
typedef float floatx4 __attribute__((ext_vector_type(4)));
typedef float f32x2 __attribute__((ext_vector_type(2)));

union B8 { int4 i; bf16x8 v; };

#if defined(__has_builtin)
#  if __has_builtin(__builtin_amdgcn_exp2f)
#    define EXP2F(x) __builtin_amdgcn_exp2f(x)
#  else
#    define EXP2F(x) exp2f(x)
#  endif
#  if __has_builtin(__builtin_amdgcn_rcpf)
#    define RCPF(x) __builtin_amdgcn_rcpf(x)
#  else
#    define RCPF(x) (1.0f / (x))
#  endif
#  if __has_builtin(__builtin_amdgcn_s_setprio)
#    define SETPRIO(p) __builtin_amdgcn_s_setprio(p)
#  else
#    define SETPRIO(p)
#  endif
#else
#  define EXP2F(x) exp2f(x)
#  define RCPF(x) (1.0f / (x))
#  define SETPRIO(p)
#endif

#define L2E  1.4426950408889634f
#define L2E2 2.8853900817779268f

__global__ __launch_bounds__(THREADS, 2)
void lstm_forecast_kernel(const float* __restrict__ x,
                          const float* __restrict__ W_ih,
                          const float* __restrict__ W_hh,
                          const float* __restrict__ b_ih,
                          const float* __restrict__ b_hh,
                          const float* __restrict__ fc_w,
                          const float* __restrict__ fc_b,
                          float* __restrict__ out) {
    // LDS: xa 64KB + h 8.5KB + fcw 1KB ~= 74KB -> 1 block/CU
    __shared__ __align__(16) uint2  xa[TSTEPS * BR];        // (x0h,x1h),(x0r,x1r) bf16 splits
    __shared__ __align__(16) __bf16 h_lds[2][BR * HPITCH];  // double-buffered h
    __shared__ __align__(16) float  fcw_lds[2][HIDDEN];

    const int tid  = threadIdx.x;
    const int wave = tid >> 6;
    const int lane = tid & 63;
    const int quad = lane >> 4;
    const int l15  = lane & 15;
    const int rb   = blockIdx.x * BR;

    if (tid < 256) fcw_lds[tid >> 7][tid & 127] = fc_w[tid];

    // ---- stage x as bf16 hi/lo splits: xa[t][row] ----
    {
        const int row = tid & 15;
        for (int tb = tid >> 4; tb < TSTEPS; tb += THREADS >> 4) {
            float2 xv = *(const float2*)&x[(size_t)(rb + row) * (2 * TSTEPS) + tb * 2];
            __bf16 x0h = (__bf16)xv.x, x1h = (__bf16)xv.y;
            __bf16 x0r = (__bf16)(xv.x - (float)x0h);
            __bf16 x1r = (__bf16)(xv.y - (float)x1h);
            uint2 d;
            d.x = (unsigned)__builtin_bit_cast(unsigned short, x0h) |
                  ((unsigned)__builtin_bit_cast(unsigned short, x1h) << 16);
            d.y = (unsigned)__builtin_bit_cast(unsigned short, x0r) |
                  ((unsigned)__builtin_bit_cast(unsigned short, x1r) << 16);
            xa[tb * BR + row] = d;
        }
    }
    for (int i = tid; i < BR * HPITCH; i += THREADS) h_lds[0][i] = (__bf16)0.0f;

    // ---- weights -> registers, pre-scaled so MFMA outputs are exp2-ready ----
    // gate scale: i,f,o -> -log2(e); g -> -2*log2(e)
    bf16x8 bfrag[4][4];   // scaled W_hh (later W_eff) fragments
    B8 bfx[4];            // scaled x+bias MFMA B-fragments (quad0 slots)
    float wih0[4], wih1[4], bsum[4], gs[4];
    const int u = wave * 16 + l15;
    const float fcb0 = fc_b[0], fcb1 = fc_b[1];
#pragma unroll
    for (int g = 0; g < 4; ++g) {
        gs[g] = (g == 2) ? -L2E2 : -L2E;
        const int cg = g * HIDDEN + u;
        wih0[g] = W_ih[cg * 2 + 0];
        wih1[g] = W_ih[cg * 2 + 1];
        bsum[g] = b_ih[cg] + b_hh[cg];
#pragma unroll
        for (int ks = 0; ks < 4; ++ks) {
            const float* wp = W_hh + (size_t)cg * HIDDEN + ks * 32 + quad * 8;
            bf16x8 bb;
#pragma unroll
            for (int j = 0; j < 8; ++j) bb[j] = (__bf16)(gs[g] * wp[j]);
            bfrag[g][ks] = bb;
        }
        B8 t; t.i = make_int4(0, 0, 0, 0);
        if (quad == 0) {
            const float w0s = gs[g] * wih0[g], w1s = gs[g] * wih1[g], bss = gs[g] * bsum[g];
            __bf16 w0h = (__bf16)w0s, w1h = (__bf16)w1s;
            __bf16 w0l = (__bf16)(w0s - (float)w0h);
            __bf16 w1l = (__bf16)(w1s - (float)w1h);
            __bf16 bh  = (__bf16)bss;
            __bf16 bl  = (__bf16)(bss - (float)bh);
            bf16x8 bv = {w0h, w1h, bh, bl, w0h, w1h, w0l, w1l};
            t.v = bv;
        }
        bfx[g] = t;
    }

    const unsigned ones2 = 0x3F803F80u;  // bf16(1.0) x2 (B rows are 0 off-quad0)

    f32x2 cst[2] = {{0.f, 0.f}, {0.f, 0.f}};   // 4 cell states as 2 packed pairs

    // elementwise on packed f32 pairs; pairwise-batched reciprocals inside each
    // packed pair (1 rcp + 3 mul replaces 2 rcp; depth-2 only).
    // 5 exp + 1 rcp per state.
    auto ew = [&](floatx4 a0, floatx4 a1, floatx4 a2, floatx4 a3, __bf16* hd) {
#pragma unroll
        for (int p = 0; p < 2; ++p) {
            const f32x2 ap0 = {a0[2*p], a0[2*p+1]};
            const f32x2 ap1 = {a1[2*p], a1[2*p+1]};
            const f32x2 ap2 = {a2[2*p], a2[2*p+1]};
            const f32x2 ap3 = {a3[2*p], a3[2*p+1]};
            f32x2 ea, eb, ec;
            ea.x = EXP2F(ap0.x); ea.y = EXP2F(ap0.y);   // e^-i (scaled)
            eb.x = EXP2F(ap2.x); eb.y = EXP2F(ap2.y);   // e^-2g
            ec.x = EXP2F(ap1.x); ec.y = EXP2F(ap1.y);   // e^-f
            const f32x2 A1 = 1.f + ea, B1 = 1.f + eb, C1 = 1.f + ec;
            const f32x2 P  = A1 * B1;
            const f32x2 PC = P * C1;
            f32x2 R;                                    // batched: 1 rcp for the pair
            {
                const float I = RCPF(PC.x * PC.y);
                R.x = I * PC.y;
                R.y = I * PC.x;
            }
            const f32x2 sfv = P * R;                    // sigmoid(f)
            const f32x2 igv = (1.f - eb) * (C1 * R);    // sigmoid(i)*tanh(g)
            const f32x2 cn  = sfv * cst[p] + igv;
            cst[p] = cn;
            const f32x2 am = -L2E2 * cn;
            f32x2 ed, eo;
            ed.x = EXP2F(fminf(am.x, 29.f));            // c clamped at -10 (tanh err < 4e-9)
            ed.y = EXP2F(fminf(am.y, 29.f));
            eo.x = EXP2F(ap3.x); eo.y = EXP2F(ap3.y);   // e^-o
            const f32x2 E = (1.f + ed) * (1.f + eo);
            f32x2 R2;                                   // batched: 1 rcp for the pair
            {
                const float J = RCPF(E.x * E.y);
                R2.x = J * E.y;
                R2.y = J * E.x;
            }
            const f32x2 hn = (1.f - ed) * R2;           // sigmoid(o)*tanh(c)
            hd[(quad * 4 + 2*p + 0) * HPITCH + u] = (__bf16)hn.x;
            hd[(quad * 4 + 2*p + 1) * HPITCH + u] = (__bf16)hn.y;
        }
    };

    auto cellE = [&](const __bf16* hs, __bf16* hd, int t) {
        const uint2 xd = xa[t * BR + l15];            // quad-broadcast, conflict-free
        B8 xf; xf.i = make_int4((int)xd.x, (int)ones2, (int)xd.y, (int)xd.x);
        bf16x8 af[4];
#pragma unroll
        for (int ks = 0; ks < 4; ++ks)
            af[ks] = *(const bf16x8*)&hs[l15 * HPITCH + ks * 32 + quad * 8];
        const floatx4 z = {0.f, 0.f, 0.f, 0.f};
        floatx4 acc[4];
        SETPRIO(1);                                    // prioritize MFMA issue
#pragma unroll
        for (int g = 0; g < 4; ++g)   // scaled x + bias folded into MFMA, zero-C init
            acc[g] = __builtin_amdgcn_mfma_f32_16x16x32_bf16(xf.v, bfx[g].v, z, 0, 0, 0);
#pragma unroll
        for (int ks = 0; ks < 4; ++ks)
#pragma unroll
            for (int g = 0; g < 4; ++g)
                acc[g] = __builtin_amdgcn_mfma_f32_16x16x32_bf16(af[ks], bfrag[g][ks], acc[g], 0, 0, 0);
        SETPRIO(0);                                    // yield to sibling wave's MFMA
        ew(acc[0], acc[1], acc[2], acc[3], hd);
        __syncthreads();
    };

    __syncthreads();

    // ================= encode: 512 steps =================
    for (int t = 0; t < TSTEPS; t += 2) {
        cellE(h_lds[0], h_lds[1], t);
        cellE(h_lds[1], h_lds[0], t + 1);
    }

    // ========== transition: fold fc into weights =========
    // W_eff = gs*(W_hh + W_ih*fc_w) ; b_eff = gs*(b + W_ih*fc_b)
    float bs2[4];
#pragma unroll
    for (int g = 0; g < 4; ++g) {
        bs2[g] = gs[g] * (bsum[g] + wih0[g] * fcb0 + wih1[g] * fcb1);
#pragma unroll
        for (int ks = 0; ks < 4; ++ks) {
            const int k0 = ks * 32 + quad * 8;
            bf16x8 bb = bfrag[g][ks];
#pragma unroll
            for (int j = 0; j < 8; ++j) {
                const float wv = (float)bb[j] + gs[g] * (wih0[g] * fcw_lds[0][k0 + j]
                                                      + wih1[g] * fcw_lds[1][k0 + j]);
                bb[j] = (__bf16)wv;
            }
            bfrag[g][ks] = bb;
        }
    }

    auto cellF = [&](const __bf16* hs, __bf16* hd) {
        bf16x8 af[4];
#pragma unroll
        for (int ks = 0; ks < 4; ++ks)
            af[ks] = *(const bf16x8*)&hs[l15 * HPITCH + ks * 32 + quad * 8];
        floatx4 acc[4];
#pragma unroll
        for (int g = 0; g < 4; ++g)
            acc[g] = (floatx4){bs2[g], bs2[g], bs2[g], bs2[g]};  // exact fp32 scaled bias
        SETPRIO(1);
#pragma unroll
        for (int ks = 0; ks < 4; ++ks)
#pragma unroll
            for (int g = 0; g < 4; ++g)
                acc[g] = __builtin_amdgcn_mfma_f32_16x16x32_bf16(af[ks], bfrag[g][ks], acc[g], 0, 0, 0);
        SETPRIO(0);
        ew(acc[0], acc[1], acc[2], acc[3], hd);
        __syncthreads();
    };

    // y output only (no feedback): wave0 computes while others run MFMA
    auto emitY = [&](const __bf16* hs, int f) {
        if (wave == 0) {
            const int r = lane & 15, seg = lane >> 4;
            const __bf16* hp = &hs[r * HPITCH + seg * 32];
            float p0 = 0.f, p1 = 0.f;
#pragma unroll
            for (int js = 0; js < 4; ++js) {
                bf16x8 hv = *(const bf16x8*)&hp[js * 8];
                const float4* f0 = (const float4*)&fcw_lds[0][seg * 32 + js * 8];
                const float4* f1 = (const float4*)&fcw_lds[1][seg * 32 + js * 8];
                float4 a0 = f0[0], b0 = f0[1], a1 = f1[0], b1 = f1[1];
                p0 += (float)hv[0]*a0.x + (float)hv[1]*a0.y + (float)hv[2]*a0.z + (float)hv[3]*a0.w
                    + (float)hv[4]*b0.x + (float)hv[5]*b0.y + (float)hv[6]*b0.z + (float)hv[7]*b0.w;
                p1 += (float)hv[0]*a1.x + (float)hv[1]*a1.y + (float)hv[2]*a1.z + (float)hv[3]*a1.w
                    + (float)hv[4]*b1.x + (float)hv[5]*b1.y + (float)hv[6]*b1.z + (float)hv[7]*b1.w;
            }
            p0 += __shfl_xor(p0, 16); p0 += __shfl_xor(p0, 32);
            p1 += __shfl_xor(p1, 16); p1 += __shfl_xor(p1, 32);
            if (seg == 0) {
                float* op = &out[(size_t)(rb + r) * (2 * NFUT) + f * 2];
                op[0] = p0 + fcb0;
                op[1] = p1 + fcb1;
            }
        }
    };

    // ================= forecast: 50 steps ================
    for (int f = 0; f < NFUT; f += 2) {
        emitY(h_lds[0], f);
        cellF(h_lds[0], h_lds[1]);
        emitY(h_lds[1], f + 1);
        cellF(h_lds[1], h_lds[0]);
    }
}

extern "C" void kernel_launch(void* const* d_in, const int* in_sizes, int n_in,
                              void* d_out, int out_size, void* d_ws, size_t ws_size,
                              hipStream_t stream) {
    const float* x    = (const float*)d_in[0];
    const float* W_ih = (const float*)d_in[1];
    const float* W_hh = (const float*)d_in[2];
    const float* b_ih = (const float*)d_in[3];
    const float* b_hh = (const float*)d_in[4];
    const float* fc_w = (const float*)d_in[5];
    const float* fc_b = (const float*)d_in[6];
    float* out = (float*)d_out;

    const int B = in_sizes[0] / (TSTEPS * 2);   // 4096
    const int grid = B / BR;                    // 256 blocks, 1 per CU
    lstm_forecast_kernel<<<grid, THREADS, 0, stream>>>(x, W_ih, W_hh, b_ih, b_hh, fc_w, fc_b, out);
}